// Round 7
// baseline (2793.137 us; speedup 1.0000x reference)
//
#include <hip/hip_runtime.h>

#define NSAMP 32768
#define INB   4
#define HIDN  4
#define CHN   2
#define OUTD  10
#define NPIX  196
#define NMID  194            /* middle BN steps, paired: 97 pairs */
#define NPAIR 97
#define BLK   512
#define NBLK  (NSAMP / BLK)  /* 64 blocks, 1 sample per thread */
#define INV_ROWS 1.52587890625e-05f   /* 1/(N*CH) = 1/65536 */
#define BN_EPS 1e-5f
#define SENTW 0xFFFFFFFFu    /* f32 sentinel: negative NaN, unreachable by finite math */
/* ws: pay[NPAIR][NBLK][256] f32 — per pair, per block, 256 moment components.
   Written once (relaxed agent u32 stores), gathered with merged sentinel-poll.
   No atomics anywhere -> deterministic. */
#define WS_BYTES ((size_t)NPAIR * NBLK * 256 * 4)

// symmetric pair list (h<=g) for C/E tensors
__device__ __constant__ int c_ph[10] = {0,0,0,0,1,1,1,2,2,3};
__device__ __constant__ int c_pg[10] = {0,1,2,3,1,2,3,2,3,3};

// Reduce-scatter over 64 lanes: v[j] holds per-lane partial of comp j.
// After 6 stages, lane ln holds the wave-total of comp ln in v[0].
__device__ __forceinline__ float scatter64(float v[64], int ln) {
#pragma unroll
    for (int b = 0; b < 6; ++b) {
        const int d = 1 << b;
        const bool hi = (ln >> b) & 1;
#pragma unroll
        for (int j = 0; j < (64 >> (b + 1)); ++j) {
            float keep = hi ? v[2 * j + 1] : v[2 * j];
            float send = hi ? v[2 * j]     : v[2 * j + 1];
            v[j] = keep + __shfl_xor(send, d);
        }
    }
    return v[0];
}

__global__ __launch_bounds__(BLK, 2)
void ttbn_main(const float* __restrict__ x,  const float* __restrict__ wf,
               const float* __restrict__ wm, const float* __restrict__ wl,
               const float* __restrict__ gamma, const float* __restrict__ beta,
               float* __restrict__ out, float* __restrict__ ws)
{
    __shared__ float wb[8][4][64];     // per-wave scatter results, 4 groups
    __shared__ float sum2[2][256];     // gather halves
    __shared__ float tot[256];         // global totals
    const int tid = threadIdx.x;
    const int ln  = tid & 63, wv = tid >> 6;
    const long n  = (long)blockIdx.x * BLK + tid;

    float gm[HIDN], bt[HIDN];
#pragma unroll
    for (int h = 0; h < HIDN; ++h) { gm[h] = gamma[h]; bt[h] = beta[h]; }

    const float* xrow = x + n * (INB * NPIX);

    // ---- initial contraction: pixel 0, no BN ----
    float y[CHN][HIDN];
    {
        float x0[INB];
#pragma unroll
        for (int i = 0; i < INB; ++i) x0[i] = xrow[i * NPIX];
#pragma unroll
        for (int c = 0; c < CHN; ++c)
#pragma unroll
            for (int h = 0; h < HIDN; ++h) {
                float acc = 0.f;
#pragma unroll
                for (int i = 0; i < INB; ++i)
                    acc = fmaf(x0[i], wf[(i * HIDN + h) * CHN + c], acc);
                y[c][h] = acc;
            }
    }
    // pair 0 pixels (1,2)
    float xa[INB], xb[INB];
#pragma unroll
    for (int i = 0; i < INB; ++i) { xa[i] = xrow[i * NPIX + 1]; xb[i] = xrow[i * NPIX + 2]; }

#pragma unroll 1
    for (int j = 0; j < NPAIR; ++j) {
        // prefetch next pair's pixels (hide under compute+sync)
        float xa2[INB], xb2[INB];
        if (j < NPAIR - 1) {
#pragma unroll
            for (int i = 0; i < INB; ++i) {
                xa2[i] = xrow[i * NPIX + 2 * j + 3];
                xb2[i] = xrow[i * NPIX + 2 * j + 4];
            }
        }
        const float* w0 = wm + (size_t)(2 * j) * 128;
        const float* w1 = w0 + 128;

        // per-sample matrices:  M[c][r][h] (step 2j), Mp[c][h][hp] (step 2j+1)
        float M[CHN][4][4], Mp[CHN][4][4];
#pragma unroll
        for (int c = 0; c < CHN; ++c)
#pragma unroll
            for (int r = 0; r < 4; ++r)
#pragma unroll
                for (int h = 0; h < 4; ++h) {
                    float a0 = 0.f, a1 = 0.f;
#pragma unroll
                    for (int i = 0; i < INB; ++i) {
                        a0 = fmaf(xa[i], w0[(r * 16 + i * 4 + h) * 2 + c], a0);
                        a1 = fmaf(xb[i], w1[(r * 16 + i * 4 + h) * 2 + c], a1);
                    }
                    M[c][r][h] = a0; Mp[c][r][h] = a1;
                }
        // raw step-t output u[c][h]
        float u[CHN][4];
#pragma unroll
        for (int c = 0; c < CHN; ++c)
#pragma unroll
            for (int h = 0; h < 4; ++h) {
                float acc = 0.f;
#pragma unroll
                for (int r = 0; r < 4; ++r) acc = fmaf(y[c][r], M[c][r][h], acc);
                u[c][h] = acc;
            }

        float bank[4];
        float v[64];
        // ---- group 0: S1(0..3) S2(4..7) A(8..23) B(24..39) ----
#pragma unroll
        for (int k = 0; k < 64; ++k) v[k] = 0.f;
#pragma unroll
        for (int c = 0; c < CHN; ++c) {
#pragma unroll
            for (int h = 0; h < 4; ++h) {
                v[h]     += u[c][h];
                v[4 + h] = fmaf(u[c][h], u[c][h], v[4 + h]);
#pragma unroll
                for (int hp = 0; hp < 4; ++hp) {
                    v[8  + h * 4 + hp] = fmaf(u[c][h], Mp[c][h][hp], v[8 + h * 4 + hp]);
                    v[24 + h * 4 + hp] += Mp[c][h][hp];
                }
            }
        }
        bank[0] = scatter64(v, ln);
        // ---- group 1: C[p][hp] = sum u_h u_g Mp_h Mp_g ----
#pragma unroll
        for (int k = 0; k < 64; ++k) v[k] = 0.f;
#pragma unroll
        for (int c = 0; c < CHN; ++c)
#pragma unroll
            for (int p = 0; p < 10; ++p) {
                const int h = c_ph[p], g = c_pg[p];
                float uu = u[c][h] * u[c][g];
#pragma unroll
                for (int hp = 0; hp < 4; ++hp) {
                    float pi = Mp[c][h][hp] * Mp[c][g][hp];
                    v[p * 4 + hp] = fmaf(uu, pi, v[p * 4 + hp]);
                }
            }
        bank[1] = scatter64(v, ln);
        // ---- group 2: D[h][g][hp] = sum u_h Mp_h Mp_g (full 4x4) ----
#pragma unroll
        for (int k = 0; k < 64; ++k) v[k] = 0.f;
#pragma unroll
        for (int c = 0; c < CHN; ++c)
#pragma unroll
            for (int h = 0; h < 4; ++h)
#pragma unroll
                for (int g = 0; g < 4; ++g)
#pragma unroll
                    for (int hp = 0; hp < 4; ++hp) {
                        float pi = Mp[c][h][hp] * Mp[c][g][hp];
                        v[(h * 4 + g) * 4 + hp] = fmaf(u[c][h], pi, v[(h * 4 + g) * 4 + hp]);
                    }
        bank[2] = scatter64(v, ln);
        // ---- group 3: E[p][hp] = sum Mp_h Mp_g ----
#pragma unroll
        for (int k = 0; k < 64; ++k) v[k] = 0.f;
#pragma unroll
        for (int c = 0; c < CHN; ++c)
#pragma unroll
            for (int p = 0; p < 10; ++p) {
                const int h = c_ph[p], g = c_pg[p];
#pragma unroll
                for (int hp = 0; hp < 4; ++hp)
                    v[p * 4 + hp] = fmaf(Mp[c][h][hp], Mp[c][g][hp], v[p * 4 + hp]);
            }
        bank[3] = scatter64(v, ln);

        // ---- cross-wave combine (8 waves) + store block payload ----
#pragma unroll
        for (int g = 0; g < 4; ++g) wb[wv][g][ln] = bank[g];
        __syncthreads();
        if (wv < 4) {
            float s = 0.f;
#pragma unroll
            for (int w = 0; w < 8; ++w) s += wb[w][wv][ln];
            unsigned* dst = (unsigned*)ws + ((size_t)j * NBLK + blockIdx.x) * 256 + wv * 64 + ln;
            __hip_atomic_store(dst, __float_as_uint(s), __ATOMIC_RELAXED, __HIP_MEMORY_SCOPE_AGENT);
        }
        // ---- merged sentinel-gather: thread (half,k) sums comp k over 32 blocks ----
        {
            const int k = tid & 255, half = tid >> 8;
            const unsigned* gp = (const unsigned*)ws + ((size_t)j * NBLK + half * 32) * 256 + k;
            float s; bool ok;
            do {
                ok = true; s = 0.f;
#pragma unroll
                for (int b = 0; b < 32; ++b) {
                    unsigned wd = __hip_atomic_load(gp + (size_t)b * 256, __ATOMIC_RELAXED,
                                                    __HIP_MEMORY_SCOPE_AGENT);
                    ok = ok && (wd != SENTW);
                    s += __uint_as_float(wd);
                }
            } while (__any(!ok));
            sum2[half][k] = s;
        }
        __syncthreads();
        if (tid < 256) tot[tid] = sum2[0][tid] + sum2[1][tid];
        __syncthreads();

        // ---- recombine (redundant per thread): BN coefs for both steps ----
        float is_[4], sh_[4];
#pragma unroll
        for (int h = 0; h < 4; ++h) {
            float m  = tot[h] * INV_ROWS;
            float va = fmaf(-m, m, tot[4 + h] * INV_ROWS);
            float r  = rsqrtf(va + BN_EPS) * gm[h];
            is_[h] = r; sh_[h] = bt[h] - m * r;
        }
        float cA[10], cE[10], cD[4][4];
#pragma unroll
        for (int p = 0; p < 10; ++p) {
            const int h = c_ph[p], g = c_pg[p];
            float f = (h == g) ? 1.f : 2.f;
            cA[p] = f * is_[h] * is_[g];
            cE[p] = f * sh_[h] * sh_[g];
        }
#pragma unroll
        for (int h = 0; h < 4; ++h)
#pragma unroll
            for (int g = 0; g < 4; ++g) cD[h][g] = 2.f * is_[h] * sh_[g];
        float is2[4], sh2[4];
#pragma unroll
        for (int hp = 0; hp < 4; ++hp) {
            float s1 = 0.f;
#pragma unroll
            for (int h = 0; h < 4; ++h) {
                s1 = fmaf(is_[h], tot[8  + h * 4 + hp], s1);
                s1 = fmaf(sh_[h], tot[24 + h * 4 + hp], s1);
            }
            float s2 = 0.f;
#pragma unroll
            for (int p = 0; p < 10; ++p) {
                s2 = fmaf(cA[p], tot[64  + p * 4 + hp], s2);
                s2 = fmaf(cE[p], tot[192 + p * 4 + hp], s2);
            }
#pragma unroll
            for (int h = 0; h < 4; ++h)
#pragma unroll
                for (int g = 0; g < 4; ++g)
                    s2 = fmaf(cD[h][g], tot[128 + (h * 4 + g) * 4 + hp], s2);
            float m2  = s1 * INV_ROWS;
            float va2 = fmaf(-m2, m2, s2 * INV_ROWS);
            float r2  = rsqrtf(va2 + BN_EPS) * gm[hp];
            is2[hp] = r2; sh2[hp] = bt[hp] - m2 * r2;
        }
        // ---- advance local state through both steps ----
#pragma unroll
        for (int c = 0; c < CHN; ++c) {
            float yp[4];
#pragma unroll
            for (int h = 0; h < 4; ++h) yp[h] = fmaf(u[c][h], is_[h], sh_[h]);
#pragma unroll
            for (int hp = 0; hp < 4; ++hp) {
                float up = 0.f;
#pragma unroll
                for (int h = 0; h < 4; ++h) up = fmaf(yp[h], Mp[c][h][hp], up);
                y[c][hp] = fmaf(up, is2[hp], sh2[hp]);
            }
        }
        if (j < NPAIR - 1) {
#pragma unroll
            for (int i = 0; i < INB; ++i) { xa[i] = xa2[i]; xb[i] = xb2[i]; }
        }
    }

    // ---- final step: pixel 195 with wl, no BN ----
    {
        float xv[INB];
#pragma unroll
        for (int i = 0; i < INB; ++i) xv[i] = xrow[i * NPIX + 195];
        float o0[OUTD], o1[OUTD];
#pragma unroll
        for (int od = 0; od < OUTD; ++od) { o0[od] = 0.f; o1[od] = 0.f; }
#pragma unroll
        for (int r = 0; r < 4; ++r)
#pragma unroll
            for (int i = 0; i < INB; ++i) {
                float p0 = y[0][r] * xv[i];
                float p1 = y[1][r] * xv[i];
                const float* wri = wl + r * (INB * OUTD * CHN) + i * (OUTD * CHN);
#pragma unroll
                for (int od = 0; od < OUTD; ++od) {
                    o0[od] = fmaf(p0, wri[od * CHN + 0], o0[od]);
                    o1[od] = fmaf(p1, wri[od * CHN + 1], o1[od]);
                }
            }
        float tmp[20];
#pragma unroll
        for (int od = 0; od < OUTD; ++od) { tmp[od] = o0[od]; tmp[10 + od] = o1[od]; }
        float4* o4 = reinterpret_cast<float4*>(out + n * (CHN * OUTD));
#pragma unroll
        for (int q = 0; q < 5; ++q)
            o4[q] = make_float4(tmp[q * 4], tmp[q * 4 + 1], tmp[q * 4 + 2], tmp[q * 4 + 3]);
    }
}

extern "C" void kernel_launch(void* const* d_in, const int* in_sizes, int n_in,
                              void* d_out, int out_size, void* d_ws, size_t ws_size,
                              hipStream_t stream) {
    const float* x     = (const float*)d_in[0];
    const float* wf    = (const float*)d_in[1];
    const float* wm    = (const float*)d_in[2];
    const float* wl    = (const float*)d_in[3];
    const float* gamma = (const float*)d_in[4];
    const float* beta  = (const float*)d_in[5];
    float*       out   = (float*)d_out;
    float*       ws    = (float*)d_ws;

    // sentinel-fill payload area (0xFF bytes == SENTW in every word)
    hipMemsetAsync(d_ws, 0xFF, WS_BYTES, stream);

    void* args[] = { &x, &wf, &wm, &wl, &gamma, &beta, &out, &ws };
    hipLaunchCooperativeKernel((void*)ttbn_main, dim3(NBLK), dim3(BLK),
                               args, 0, stream);
}

// Round 8
// 2136.787 us; speedup vs baseline: 1.3072x; 1.3072x over previous
//
#include <hip/hip_runtime.h>

#define NSAMP 32768
#define INB   4
#define HIDN  4
#define CHN   2
#define OUTD  10
#define NPIX  196
#define NPAIR 97             /* 194 middle BN steps, processed 2 per grid sync */
#define BLK   512
#define NBLK  (NSAMP / BLK)  /* 64 blocks, 1 sample per thread */
#define NCOMP 192            /* 184 moment comps + 8 pad */
#define INV_ROWS 1.52587890625e-05f   /* 1/(N*CH) = 1/65536 */
#define BN_EPS 1e-5f
#define SENTW 0xFFFFFFFFu    /* negative-NaN sentinel, unreachable by finite math */
/* ws: pay[NPAIR][NBLK][NCOMP] f32, relaxed agent u32 stores; merged sentinel-
   gather (per-word check -> word atomicity suffices). No atomics, deterministic. */
#define WS_BYTES ((size_t)NPAIR * NBLK * NCOMP * 4)

/* Moment layout (totals, also LDS 'tot'):
   0-3 S1[h] | 4-7 S2[h] | 8-23 A[h][hp]=Σ u_h Mp_h,hp | 24-39 B[h][hp]=Σ Mp_h,hp
   40-79 C[p][hp]=Σ u_h u_g Mp_h Mp_g (sym pairs) | 80-143 D[h][g][hp]=Σ u_h Mp_h Mp_g
   144-183 E[p][hp]=Σ Mp_h Mp_g | 184-191 pad */

__device__ __forceinline__ float comp_val(const int k, const float u[CHN][4],
                                          const float Mp[CHN][4][4]) {
    constexpr int ph[10] = {0,0,0,0,1,1,1,2,2,3};
    constexpr int pg[10] = {0,1,2,3,1,2,3,2,3,3};
    float s = 0.f;
    if (k < 4) {
#pragma unroll
        for (int c = 0; c < CHN; ++c) s += u[c][k];
    } else if (k < 8) {
        const int h = k - 4;
#pragma unroll
        for (int c = 0; c < CHN; ++c) s = fmaf(u[c][h], u[c][h], s);
    } else if (k < 24) {
        const int h = (k - 8) >> 2, hp = k & 3;
#pragma unroll
        for (int c = 0; c < CHN; ++c) s = fmaf(u[c][h], Mp[c][h][hp], s);
    } else if (k < 40) {
        const int h = (k - 24) >> 2, hp = k & 3;
#pragma unroll
        for (int c = 0; c < CHN; ++c) s += Mp[c][h][hp];
    } else if (k < 80) {
        const int p = (k - 40) >> 2, hp = k & 3, h = ph[p], g = pg[p];
#pragma unroll
        for (int c = 0; c < CHN; ++c)
            s = fmaf(u[c][h] * u[c][g], Mp[c][h][hp] * Mp[c][g][hp], s);
    } else if (k < 144) {
        const int idx = k - 80, h = idx >> 4, g = (idx >> 2) & 3, hp = k & 3;
#pragma unroll
        for (int c = 0; c < CHN; ++c)
            s = fmaf(u[c][h], Mp[c][h][hp] * Mp[c][g][hp], s);
    } else if (k < 184) {
        const int p = (k - 144) >> 2, hp = k & 3, h = ph[p], g = pg[p];
#pragma unroll
        for (int c = 0; c < CHN; ++c) s = fmaf(Mp[c][h][hp], Mp[c][g][hp], s);
    }
    return s;
}

/* Reduce over 64 lanes of 32 per-lane partials; lane ln ends holding the
   wave-total of comp (ln&31). Peak live set: 32 regs. */
__device__ __forceinline__ float scatter32(float v[32], int ln) {
#pragma unroll
    for (int j = 0; j < 32; ++j) v[j] += __shfl_xor(v[j], 32);
#pragma unroll
    for (int b = 0; b < 5; ++b) {
        const int d = 1 << b;
        const bool hi = (ln >> b) & 1;
#pragma unroll
        for (int j = 0; j < (32 >> (b + 1)); ++j) {
            float keep = hi ? v[2 * j + 1] : v[2 * j];
            float send = hi ? v[2 * j]     : v[2 * j + 1];
            v[j] = keep + __shfl_xor(send, d);
        }
    }
    return v[0];
}

__global__ __launch_bounds__(BLK, 2)
void ttbn_main(const float* __restrict__ x,  const float* __restrict__ wf,
               const float* __restrict__ wm, const float* __restrict__ wl,
               const float* __restrict__ gamma, const float* __restrict__ beta,
               float* __restrict__ out, float* __restrict__ ws)
{
    __shared__ float wb[8][6][32];     // per-wave scatter results
    __shared__ float sum2[2][NCOMP];   // gather halves
    __shared__ float tot[NCOMP];       // grid totals
    const int tid = threadIdx.x;
    const int ln  = tid & 63, wv = tid >> 6;
    const long n  = (long)blockIdx.x * BLK + tid;

    float gm[HIDN], bt[HIDN];
#pragma unroll
    for (int h = 0; h < HIDN; ++h) { gm[h] = gamma[h]; bt[h] = beta[h]; }

    const float* xrow = x + n * (INB * NPIX);

    // ---- pixel 0 (no BN) ----
    float y[CHN][HIDN];
    {
        float x0[INB];
#pragma unroll
        for (int i = 0; i < INB; ++i) x0[i] = xrow[i * NPIX];
#pragma unroll
        for (int c = 0; c < CHN; ++c)
#pragma unroll
            for (int h = 0; h < HIDN; ++h) {
                float acc = 0.f;
#pragma unroll
                for (int i = 0; i < INB; ++i)
                    acc = fmaf(x0[i], wf[(i * HIDN + h) * CHN + c], acc);
                y[c][h] = acc;
            }
    }
    float xa[INB], xb[INB];   // pair-0 pixels (1,2)
#pragma unroll
    for (int i = 0; i < INB; ++i) { xa[i] = xrow[i * NPIX + 1]; xb[i] = xrow[i * NPIX + 2]; }

#pragma unroll 1
    for (int j = 0; j < NPAIR; ++j) {
        const float* w0 = wm + (size_t)(2 * j) * 128;
        const float* w1 = w0 + 128;

        // u = y · M(xa,w0), M streamed (never materialized)
        float u[CHN][HIDN] = {{0.f,0.f,0.f,0.f},{0.f,0.f,0.f,0.f}};
#pragma unroll
        for (int r = 0; r < 4; ++r)
#pragma unroll
            for (int h = 0; h < 4; ++h)
#pragma unroll
                for (int c = 0; c < CHN; ++c) {
                    float m = 0.f;
#pragma unroll
                    for (int i = 0; i < INB; ++i)
                        m = fmaf(xa[i], w0[(r * 16 + i * 4 + h) * 2 + c], m);
                    u[c][h] = fmaf(y[c][r], m, u[c][h]);
                }
        // Mp(xb,w1)
        float Mp[CHN][4][4];
#pragma unroll
        for (int r = 0; r < 4; ++r)
#pragma unroll
            for (int h = 0; h < 4; ++h)
#pragma unroll
                for (int c = 0; c < CHN; ++c) {
                    float m = 0.f;
#pragma unroll
                    for (int i = 0; i < INB; ++i)
                        m = fmaf(xb[i], w1[(r * 16 + i * 4 + h) * 2 + c], m);
                    Mp[c][r][h] = m;
                }
        // prefetch next pair's pixels (hides HBM latency under moments+sync)
        float xa2[INB], xb2[INB];
        if (j < NPAIR - 1) {
#pragma unroll
            for (int i = 0; i < INB; ++i) {
                xa2[i] = xrow[i * NPIX + 2 * j + 3];
                xb2[i] = xrow[i * NPIX + 2 * j + 4];
            }
        }
        // ---- 6 banks of 32 comps: compute + reduce-scatter ----
        float bank[6];
#pragma unroll
        for (int b = 0; b < 6; ++b) {
            float v[32];
#pragma unroll
            for (int q = 0; q < 32; ++q) v[q] = comp_val(b * 32 + q, u, Mp);
            bank[b] = scatter32(v, ln);
        }
        if (ln < 32) {
#pragma unroll
            for (int b = 0; b < 6; ++b) wb[wv][b][ln] = bank[b];
        }
        __syncthreads();
        // cross-wave combine + payload store (192 threads)
        if (tid < NCOMP) {
            float s = 0.f;
#pragma unroll
            for (int w = 0; w < 8; ++w) s += wb[w][tid >> 5][tid & 31];
            __hip_atomic_store((unsigned*)ws + ((size_t)j * NBLK + blockIdx.x) * NCOMP + tid,
                               __float_as_uint(s), __ATOMIC_RELAXED, __HIP_MEMORY_SCOPE_AGENT);
        }
        // merged sentinel-gather: thread (half,k) sums comp k over 32 blocks
        if (tid < 2 * NCOMP) {
            const int half = tid >= NCOMP ? 1 : 0;
            const int k = tid - half * NCOMP;
            const unsigned* gp = (const unsigned*)ws + ((size_t)j * NBLK + half * 32) * NCOMP + k;
            float s; bool ok;
            do {
                ok = true; s = 0.f;
#pragma unroll
                for (int b = 0; b < 32; ++b) {
                    unsigned wd = __hip_atomic_load(gp + (size_t)b * NCOMP, __ATOMIC_RELAXED,
                                                    __HIP_MEMORY_SCOPE_AGENT);
                    ok = ok && (wd != SENTW);
                    s += __uint_as_float(wd);
                }
            } while (__any(!ok));
            sum2[half][k] = s;
        }
        __syncthreads();
        if (tid < NCOMP) tot[tid] = sum2[0][tid] + sum2[1][tid];
        __syncthreads();

        // ---- recombine BN coefs for both steps (redundant per thread) ----
        constexpr int ph[10] = {0,0,0,0,1,1,1,2,2,3};
        constexpr int pg[10] = {0,1,2,3,1,2,3,2,3,3};
        float is_[4], sh_[4];
#pragma unroll
        for (int h = 0; h < 4; ++h) {
            float m  = tot[h] * INV_ROWS;
            float va = fmaf(-m, m, tot[4 + h] * INV_ROWS);
            float r  = rsqrtf(va + BN_EPS) * gm[h];
            is_[h] = r; sh_[h] = bt[h] - m * r;
        }
        float is2[4], sh2[4];
#pragma unroll
        for (int hp = 0; hp < 4; ++hp) {
            float s1 = 0.f;
#pragma unroll
            for (int h = 0; h < 4; ++h) {
                s1 = fmaf(is_[h], tot[8  + h * 4 + hp], s1);
                s1 = fmaf(sh_[h], tot[24 + h * 4 + hp], s1);
            }
            float s2 = 0.f;
#pragma unroll
            for (int p = 0; p < 10; ++p) {
                const int h = ph[p], g = pg[p];
                const float f = (h == g) ? 1.f : 2.f;
                s2 = fmaf(f * is_[h] * is_[g], tot[40  + p * 4 + hp], s2);
                s2 = fmaf(f * sh_[h] * sh_[g], tot[144 + p * 4 + hp], s2);
            }
#pragma unroll
            for (int h = 0; h < 4; ++h)
#pragma unroll
                for (int g = 0; g < 4; ++g)
                    s2 = fmaf(2.f * is_[h] * sh_[g], tot[80 + (h * 4 + g) * 4 + hp], s2);
            float m2  = s1 * INV_ROWS;
            float va2 = fmaf(-m2, m2, s2 * INV_ROWS);
            float r2  = rsqrtf(va2 + BN_EPS) * gm[hp];
            is2[hp] = r2; sh2[hp] = bt[hp] - m2 * r2;
        }
        // ---- advance state through both steps ----
#pragma unroll
        for (int c = 0; c < CHN; ++c) {
            float yp[4];
#pragma unroll
            for (int h = 0; h < 4; ++h) yp[h] = fmaf(u[c][h], is_[h], sh_[h]);
#pragma unroll
            for (int hp = 0; hp < 4; ++hp) {
                float up = 0.f;
#pragma unroll
                for (int h = 0; h < 4; ++h) up = fmaf(yp[h], Mp[c][h][hp], up);
                y[c][hp] = fmaf(up, is2[hp], sh2[hp]);
            }
        }
        if (j < NPAIR - 1) {
#pragma unroll
            for (int i = 0; i < INB; ++i) { xa[i] = xa2[i]; xb[i] = xb2[i]; }
        }
    }

    // ---- final step: pixel 195 with wl, no BN ----
    {
        float xv[INB];
#pragma unroll
        for (int i = 0; i < INB; ++i) xv[i] = xrow[i * NPIX + 195];
        float o0[OUTD], o1[OUTD];
#pragma unroll
        for (int od = 0; od < OUTD; ++od) { o0[od] = 0.f; o1[od] = 0.f; }
#pragma unroll
        for (int r = 0; r < 4; ++r)
#pragma unroll
            for (int i = 0; i < INB; ++i) {
                float p0 = y[0][r] * xv[i];
                float p1 = y[1][r] * xv[i];
                const float* wri = wl + r * (INB * OUTD * CHN) + i * (OUTD * CHN);
#pragma unroll
                for (int od = 0; od < OUTD; ++od) {
                    o0[od] = fmaf(p0, wri[od * CHN + 0], o0[od]);
                    o1[od] = fmaf(p1, wri[od * CHN + 1], o1[od]);
                }
            }
        float tmp[20];
#pragma unroll
        for (int od = 0; od < OUTD; ++od) { tmp[od] = o0[od]; tmp[10 + od] = o1[od]; }
        float4* o4 = reinterpret_cast<float4*>(out + n * (CHN * OUTD));
#pragma unroll
        for (int q = 0; q < 5; ++q)
            o4[q] = make_float4(tmp[q * 4], tmp[q * 4 + 1], tmp[q * 4 + 2], tmp[q * 4 + 3]);
    }
}

extern "C" void kernel_launch(void* const* d_in, const int* in_sizes, int n_in,
                              void* d_out, int out_size, void* d_ws, size_t ws_size,
                              hipStream_t stream) {
    const float* x     = (const float*)d_in[0];
    const float* wf    = (const float*)d_in[1];
    const float* wm    = (const float*)d_in[2];
    const float* wl    = (const float*)d_in[3];
    const float* gamma = (const float*)d_in[4];
    const float* beta  = (const float*)d_in[5];
    float*       out   = (float*)d_out;
    float*       ws    = (float*)d_ws;

    // sentinel-fill payload area (0xFF bytes == SENTW in every word)
    hipMemsetAsync(d_ws, 0xFF, WS_BYTES, stream);

    void* args[] = { &x, &wf, &wm, &wl, &gamma, &beta, &out, &ws };
    hipLaunchCooperativeKernel((void*)ttbn_main, dim3(NBLK), dim3(BLK),
                               args, 0, stream);
}

// Round 9
// 848.658 us; speedup vs baseline: 3.2912x; 2.5178x over previous
//
#include <hip/hip_runtime.h>

#define NSAMP 32768
#define INB   4
#define HIDN  4
#define CHN   2
#define OUTD  10
#define NPIX  196
#define NMID  194
#define BLK   256
#define SPT   2                        /* samples per thread */
#define NBLK  (NSAMP / (BLK * SPT))    /* 64 blocks == wave width */
#define INV_ROWS 1.52587890625e-05f    /* 1 / (N*CH) = 1/65536 */
#define BN_EPS 1e-5f
#define SENT  0xFFFFFFFFFFFFFFFFull    /* NaN-pair sentinel, unreachable by finite math */
/* ws: slots[NMID][NBLK][4] u64 — 32B per block-slot. ONLY WAVE 0 of each block
   does any global traffic in the sync: lanes 0-3 store the block partial,
   all 64 lanes poll (lane l watches block l, coalesced), butterfly, and
   publish the 8 totals via LDS. Waves 1-3 never touch the LLC -> the
   broadcast fan-out that serialized R2-R5 (~4.5us/step invariant) is gone. */
#define WS_BYTES ((size_t)NMID * NBLK * 4 * sizeof(unsigned long long))

__device__ __forceinline__ float xcomp(const float4& v, int j) {
    return j == 0 ? v.x : j == 1 ? v.y : j == 2 ? v.z : v.w;
}

__device__ __forceinline__ void mid_step(
    int t, const float xv[SPT][INB], float y[SPT][CHN][HIDN],
    const float* __restrict__ wm,
    const float gm[HIDN], const float bt[HIDN],
    unsigned long long* __restrict__ slots,
    float (*pb)[8], float* totl, int tid)
{
    const float* w = wm + (long)t * (HIDN * INB * HIDN * CHN);  // 128 floats, uniform
    float yn[SPT][CHN][HIDN];
#pragma unroll
    for (int s = 0; s < SPT; ++s)
#pragma unroll
        for (int c = 0; c < CHN; ++c)
#pragma unroll
            for (int h = 0; h < HIDN; ++h) yn[s][c][h] = 0.f;

#pragma unroll
    for (int s = 0; s < SPT; ++s)
#pragma unroll
        for (int r = 0; r < HIDN; ++r)
#pragma unroll
            for (int i = 0; i < INB; ++i) {
                float p0 = y[s][0][r] * xv[s][i];
                float p1 = y[s][1][r] * xv[s][i];
                const float* wri = w + r * (INB * HIDN * CHN) + i * (HIDN * CHN);
#pragma unroll
                for (int h = 0; h < HIDN; ++h) {
                    yn[s][0][h] = fmaf(p0, wri[h * CHN + 0], yn[s][0][h]);
                    yn[s][1][h] = fmaf(p1, wri[h * CHN + 1], yn[s][1][h]);
                }
            }
    // per-thread partials: sum / sumsq per h over samples+channels
    float red[8];
#pragma unroll
    for (int h = 0; h < HIDN; ++h) {
        float sm = 0.f, sq = 0.f;
#pragma unroll
        for (int s = 0; s < SPT; ++s) {
            sm += yn[s][0][h] + yn[s][1][h];
            sq += yn[s][0][h] * yn[s][0][h] + yn[s][1][h] * yn[s][1][h];
        }
        red[h] = sm; red[4 + h] = sq;
    }
    // wave(64) reduce -> lane 0 of each wave
#pragma unroll
    for (int j = 0; j < 8; ++j)
#pragma unroll
        for (int off = 32; off > 0; off >>= 1)
            red[j] += __shfl_down(red[j], off);
    const int wv = tid >> 6, ln = tid & 63;
    if (ln == 0) {
#pragma unroll
        for (int j = 0; j < 8; ++j) pb[wv][j] = red[j];
    }
    __syncthreads();                       // pb ready
    if (wv == 0) {
        // lanes 0-3: combine 4 waves, store block partial (2 floats / lane)
        if (ln < 4) {
            float lo = pb[0][2 * ln]     + pb[1][2 * ln]     + pb[2][2 * ln]     + pb[3][2 * ln];
            float hi = pb[0][2 * ln + 1] + pb[1][2 * ln + 1] + pb[2][2 * ln + 1] + pb[3][2 * ln + 1];
            unsigned long long v = ((unsigned long long)__float_as_uint(hi) << 32)
                                 |  (unsigned long long)__float_as_uint(lo);
            __hip_atomic_store(&slots[((size_t)t * NBLK + blockIdx.x) * 4 + ln], v,
                               __ATOMIC_RELAXED, __HIP_MEMORY_SCOPE_AGENT);
        }
        // all 64 lanes: poll block ln's slot (coalesced 2KB wave read)
        const unsigned long long* ps = &slots[((size_t)t * NBLK + ln) * 4];
        unsigned long long q0, q1, q2, q3;
        do {
            q0 = __hip_atomic_load(&ps[0], __ATOMIC_RELAXED, __HIP_MEMORY_SCOPE_AGENT);
            q1 = __hip_atomic_load(&ps[1], __ATOMIC_RELAXED, __HIP_MEMORY_SCOPE_AGENT);
            q2 = __hip_atomic_load(&ps[2], __ATOMIC_RELAXED, __HIP_MEMORY_SCOPE_AGENT);
            q3 = __hip_atomic_load(&ps[3], __ATOMIC_RELAXED, __HIP_MEMORY_SCOPE_AGENT);
        } while (!__all(q0 != SENT && q1 != SENT && q2 != SENT && q3 != SENT));
        // lane ln holds block ln's 8 partials; butterfly-sum across lanes
        float sm[8];
        sm[0] = __uint_as_float((unsigned)q0); sm[1] = __uint_as_float((unsigned)(q0 >> 32));
        sm[2] = __uint_as_float((unsigned)q1); sm[3] = __uint_as_float((unsigned)(q1 >> 32));
        sm[4] = __uint_as_float((unsigned)q2); sm[5] = __uint_as_float((unsigned)(q2 >> 32));
        sm[6] = __uint_as_float((unsigned)q3); sm[7] = __uint_as_float((unsigned)(q3 >> 32));
#pragma unroll
        for (int j = 0; j < 8; ++j)
#pragma unroll
            for (int off = 1; off < 64; off <<= 1)
                sm[j] += __shfl_xor(sm[j], off);
        if (ln < 8) totl[ln] = sm[ln];     // publish totals via LDS
    }
    __syncthreads();                       // totals visible to all waves
    float sm[8];
#pragma unroll
    for (int j = 0; j < 8; ++j) sm[j] = totl[j];
#pragma unroll
    for (int h = 0; h < HIDN; ++h) {
        float m  = sm[h] * INV_ROWS;
        float v  = fmaf(-m, m, sm[4 + h] * INV_ROWS);
        float is = rsqrtf(v + BN_EPS) * gm[h];
        float sh = bt[h] - m * is;
#pragma unroll
        for (int s = 0; s < SPT; ++s) {
            y[s][0][h] = fmaf(yn[s][0][h], is, sh);
            y[s][1][h] = fmaf(yn[s][1][h], is, sh);
        }
    }
}

__global__ __launch_bounds__(BLK, 1)
void ttbn_main(const float* __restrict__ x,  const float* __restrict__ wf,
               const float* __restrict__ wm, const float* __restrict__ wl,
               const float* __restrict__ gamma, const float* __restrict__ beta,
               float* __restrict__ out, unsigned long long* __restrict__ slots)
{
    __shared__ float pb[BLK / 64][8];
    __shared__ float totl[8];
    const int tid = threadIdx.x;

    float gm[HIDN], bt[HIDN];
#pragma unroll
    for (int h = 0; h < HIDN; ++h) { gm[h] = gamma[h]; bt[h] = beta[h]; }

    const float* xn[SPT];
    long nidx[SPT];
#pragma unroll
    for (int s = 0; s < SPT; ++s) {
        nidx[s] = (long)blockIdx.x * (BLK * SPT) + s * BLK + tid;
        xn[s]   = x + nidx[s] * (INB * NPIX);
    }

    float4 xg[SPT][INB];          // 4 pixels x 4 bonds x SPT samples
    float  y[SPT][CHN][HIDN];

    // ---- group 0: pixels 0..3 ----
#pragma unroll
    for (int s = 0; s < SPT; ++s)
#pragma unroll
        for (int i = 0; i < INB; ++i)
            xg[s][i] = *reinterpret_cast<const float4*>(xn[s] + i * NPIX);

#pragma unroll
    for (int s = 0; s < SPT; ++s)
#pragma unroll
        for (int c = 0; c < CHN; ++c)
#pragma unroll
            for (int h = 0; h < HIDN; ++h) {
                float acc = 0.f;
#pragma unroll
                for (int i = 0; i < INB; ++i)
                    acc = fmaf(xg[s][i].x, wf[i * (HIDN * CHN) + h * CHN + c], acc);
                y[s][c][h] = acc;
            }
#pragma unroll
    for (int slp = 1; slp < 4; ++slp) {
        float xv[SPT][INB];
#pragma unroll
        for (int s = 0; s < SPT; ++s)
#pragma unroll
            for (int i = 0; i < INB; ++i) xv[s][i] = xcomp(xg[s][i], slp);
        mid_step(slp - 1, xv, y, wm, gm, bt, slots, pb, totl, tid);
    }

    // ---- groups 1..47: pixels 4g..4g+3 ----
#pragma unroll 1
    for (int g = 1; g < 48; ++g) {
#pragma unroll
        for (int s = 0; s < SPT; ++s)
#pragma unroll
            for (int i = 0; i < INB; ++i)
                xg[s][i] = *reinterpret_cast<const float4*>(xn[s] + i * NPIX + g * 4);
#pragma unroll
        for (int slp = 0; slp < 4; ++slp) {
            float xv[SPT][INB];
#pragma unroll
            for (int s = 0; s < SPT; ++s)
#pragma unroll
                for (int i = 0; i < INB; ++i) xv[s][i] = xcomp(xg[s][i], slp);
            mid_step(g * 4 + slp - 1, xv, y, wm, gm, bt, slots, pb, totl, tid);
        }
    }

    // ---- group 48: pixels 192..195 ----
#pragma unroll
    for (int s = 0; s < SPT; ++s)
#pragma unroll
        for (int i = 0; i < INB; ++i)
            xg[s][i] = *reinterpret_cast<const float4*>(xn[s] + i * NPIX + 192);
#pragma unroll
    for (int slp = 0; slp < 3; ++slp) {   // pixels 192..194 -> t = 191..193
        float xv[SPT][INB];
#pragma unroll
        for (int s = 0; s < SPT; ++s)
#pragma unroll
            for (int i = 0; i < INB; ++i) xv[s][i] = xcomp(xg[s][i], slp);
        mid_step(191 + slp, xv, y, wm, gm, bt, slots, pb, totl, tid);
    }
    // pixel 195: out[n,0,c,o] = sum_{r,i} y[c][r]*x_i*wl[r,i,o,c]
#pragma unroll
    for (int s = 0; s < SPT; ++s) {
        float xv[INB];
#pragma unroll
        for (int i = 0; i < INB; ++i) xv[i] = xg[s][i].w;
        float o0[OUTD], o1[OUTD];
#pragma unroll
        for (int od = 0; od < OUTD; ++od) { o0[od] = 0.f; o1[od] = 0.f; }
#pragma unroll
        for (int r = 0; r < 4; ++r)
#pragma unroll
            for (int i = 0; i < INB; ++i) {
                float p0 = y[s][0][r] * xv[i];
                float p1 = y[s][1][r] * xv[i];
                const float* wri = wl + r * (INB * OUTD * CHN) + i * (OUTD * CHN);
#pragma unroll
                for (int od = 0; od < OUTD; ++od) {
                    o0[od] = fmaf(p0, wri[od * CHN + 0], o0[od]);
                    o1[od] = fmaf(p1, wri[od * CHN + 1], o1[od]);
                }
            }
        float tmp[20];
#pragma unroll
        for (int od = 0; od < OUTD; ++od) { tmp[od] = o0[od]; tmp[10 + od] = o1[od]; }
        float4* o4 = reinterpret_cast<float4*>(out + nidx[s] * (CHN * OUTD));
#pragma unroll
        for (int q = 0; q < 5; ++q)
            o4[q] = make_float4(tmp[q * 4], tmp[q * 4 + 1], tmp[q * 4 + 2], tmp[q * 4 + 3]);
    }
}

extern "C" void kernel_launch(void* const* d_in, const int* in_sizes, int n_in,
                              void* d_out, int out_size, void* d_ws, size_t ws_size,
                              hipStream_t stream) {
    const float* x     = (const float*)d_in[0];
    const float* wf    = (const float*)d_in[1];
    const float* wm    = (const float*)d_in[2];
    const float* wl    = (const float*)d_in[3];
    const float* gamma = (const float*)d_in[4];
    const float* beta  = (const float*)d_in[5];
    float*       out   = (float*)d_out;
    unsigned long long* slots = (unsigned long long*)d_ws;

    // sentinel-fill the slot array (0xFF bytes == SENT); stream-ordered before kernel
    hipMemsetAsync(d_ws, 0xFF, WS_BYTES, stream);

    void* args[] = { &x, &wf, &wm, &wl, &gamma, &beta, &out, &slots };
    hipLaunchCooperativeKernel((void*)ttbn_main, dim3(NBLK), dim3(BLK),
                               args, 0, stream);
}